// Round 5
// baseline (541.903 us; speedup 1.0000x reference)
//
#include <hip/hip_runtime.h>
#include <stdint.h>

// Problem constants (B=8, M=4096, N=K=1024, D=1024)
#define RROWS 32768   // B*M
#define KDIM  1024    // N
#define DDIM  1024

typedef __bf16 bf16;
typedef __bf16 bf16x4 __attribute__((ext_vector_type(4)));
typedef __bf16 bf16x8 __attribute__((ext_vector_type(8)));
typedef float  f32x4  __attribute__((ext_vector_type(4)));

typedef __attribute__((address_space(1))) const unsigned int* gas_ptr;
typedef __attribute__((address_space(3))) unsigned int* las_ptr;

// ---------------------------------------------------------------------------
// Prep 1: Gt[d][k] = gamma[k] * w[k][d]  (bf16, transposed). 64x64 LDS tiles.
// ---------------------------------------------------------------------------
__global__ __launch_bounds__(256) void prep_gt(const float* __restrict__ w,
                                               const float* __restrict__ gamma,
                                               bf16* __restrict__ Gt) {
    __shared__ float tile[64][65];
    const int k0 = blockIdx.x * 64;
    const int d0 = blockIdx.y * 64;
    const int t  = threadIdx.x;
    const int col4 = (t & 15) * 4;
    const int rowb = t >> 4;
#pragma unroll
    for (int r = 0; r < 4; ++r) {
        const int k = rowb + r * 16;
        const float4 v = *(const float4*)&w[(size_t)(k0 + k) * DDIM + d0 + col4];
        const float g = gamma[k0 + k];
        tile[k][col4 + 0] = v.x * g;
        tile[k][col4 + 1] = v.y * g;
        tile[k][col4 + 2] = v.z * g;
        tile[k][col4 + 3] = v.w * g;
    }
    __syncthreads();
#pragma unroll
    for (int r = 0; r < 2; ++r) {
        const int d  = (t >> 3) + r * 32;
        const int ks = (t & 7) * 8;
        bf16x8 o;
#pragma unroll
        for (int j = 0; j < 8; ++j) o[j] = (bf16)tile[ks + j][d];
        *(bf16x8*)&Gt[(size_t)(d0 + d) * KDIM + k0 + ks] = o;
    }
}

// ---------------------------------------------------------------------------
// Prep 2a/2b: gw[d] = sum_k gamma*w, cvec[d] = sum_k beta*w + b
// (both needed by the fused epilogue correction)
// ---------------------------------------------------------------------------
__global__ __launch_bounds__(256) void prep_part(const float* __restrict__ w,
                                                 const float* __restrict__ gamma,
                                                 const float* __restrict__ beta,
                                                 float* __restrict__ partG,
                                                 float* __restrict__ partB) {
    const int d  = blockIdx.x * 256 + threadIdx.x;
    const int kc = blockIdx.y;
    float ag = 0.f, ab = 0.f;
    for (int k = kc * 64; k < kc * 64 + 64; ++k) {
        const float wv = w[(size_t)k * DDIM + d];
        ag += gamma[k] * wv;
        ab += beta[k] * wv;
    }
    partG[(size_t)kc * DDIM + d] = ag;
    partB[(size_t)kc * DDIM + d] = ab;
}

__global__ __launch_bounds__(256) void prep_reduce(const float* __restrict__ partG,
                                                   const float* __restrict__ partB,
                                                   const float* __restrict__ b,
                                                   float* __restrict__ gw,
                                                   float* __restrict__ cvec) {
    const int d = blockIdx.x * 256 + threadIdx.x;
    float g = 0.f, a = 0.f;
#pragma unroll
    for (int j = 0; j < 16; ++j) {
        g += partG[(size_t)j * DDIM + d];
        a += partB[(size_t)j * DDIM + d];
    }
    gw[d]   = g;
    cvec[d] = a + b[d];
}

// ---------------------------------------------------------------------------
// Fused LN+GEMM: out[r][d] = rstd[r]*(sum_k bf16(x[r,k])*Gt[d,k] - mean[r]*gw[d]) + cvec[d]
//
// 256x256 tile, BK=64, 8 waves (2Mx4N), round-2's 4-phase quadrant schedule
// (best measured: 85us, 0 bank conflicts). Changes vs round 2:
//   - A staged from f32 x via registers: 4x dwordx4 -> cvt bf16 -> swizzled
//     ds_write_b64 (write pattern covers all 32 banks uniformly = conflict-free).
//     Row stats (s1,s2) accumulated for free from the staging registers.
//   - B (Gt) staged via global_load_lds as before (chunk-XOR, 0-conflict).
//   - Safety: within a tile iteration all LDS reads hit buffer c, all writes
//     hit buffer o; the per-tile __syncthreads (vmcnt0+lgkmcnt0 drain) fences
//     the cross-iteration hazard. Raw s_barriers are scheduling-only.
//   - Epilogue applies the LN correction (algebra verified by the previous
//     session's fused fallback kernel).
// Eliminates the ln_convert pass (192 MB traffic) and the xb workspace.
// ---------------------------------------------------------------------------
__device__ __forceinline__ void stage_half(const bf16* __restrict__ g0,
                                           bf16* lhalf, int kt, int rowOff, int tid) {
#pragma unroll
    for (int j = 0; j < 2; ++j) {
        const int ci = j * 512 + tid;        // 16B chunk index 0..1023 (16KB)
        const int rl = ci >> 3;              // row within half 0..127
        const int q  = (ci & 7) ^ (rl & 7);  // source k-chunk for this slot
        const bf16* gp = g0 + (size_t)(rowOff + rl) * KDIM + kt * 64 + q * 8;
        char* lp = (char*)lhalf + ci * 16;
        __builtin_amdgcn_global_load_lds((gas_ptr)(const void*)gp,
                                         (las_ptr)(void*)lp, 16, 0, 0);
    }
}

__device__ __forceinline__ bf16x8 ld_frag(const bf16* base, int row, int qk) {
    return *(const bf16x8*)(base + row * 64 + (qk ^ (row & 7)) * 8);
}

#define MFMA_Q(MO, NO, AFR, BFR)                                               \
    __builtin_amdgcn_s_setprio(1);                                             \
    _Pragma("unroll")                                                          \
    for (int kk_ = 0; kk_ < 2; ++kk_) {                                        \
        _Pragma("unroll")                                                      \
        for (int mm_ = 0; mm_ < 4; ++mm_) {                                    \
            _Pragma("unroll")                                                  \
            for (int nn_ = 0; nn_ < 2; ++nn_)                                  \
                acc[(MO) + mm_][(NO) + nn_] =                                  \
                    __builtin_amdgcn_mfma_f32_16x16x32_bf16(                   \
                        AFR[mm_][kk_], BFR[nn_][kk_],                          \
                        acc[(MO) + mm_][(NO) + nn_], 0, 0, 0);                 \
        }                                                                      \
    }                                                                          \
    __builtin_amdgcn_s_setprio(0);

// A staging: half H (0 = rows 0-127, 1 = rows 128-255), K-tile KT.
// Each thread: 4 chunks ci = j*512+tid; row = H*128 + (ci>>4); 4 floats at
// col (ci&15)*4. Wave access = 4 rows x 256B contiguous -> perfect coalescing.
#define A_ISSUE(H, KT)                                                         \
    _Pragma("unroll")                                                          \
    for (int j = 0; j < 4; ++j) {                                              \
        const int ci = j * 512 + tid;                                          \
        va[j] = *(const float4*)&xg[(size_t)((H) * 128 + (ci >> 4)) * KDIM +   \
                                    (KT) * 64 + (ci & 15) * 4];                \
    }

// cvt + swizzled LDS write (slot = (c16>>1) ^ (r&7), 8B half by c16&1) +
// free stats accumulation. Write instr hits 8 slot-groups x 8 lanes uniform.
#define A_WRITE(H, BUF)                                                        \
    _Pragma("unroll")                                                          \
    for (int j = 0; j < 4; ++j) {                                              \
        const int ci  = j * 512 + tid;                                         \
        const int r   = (H) * 128 + (ci >> 4);                                 \
        const int c16 = ci & 15;                                               \
        const float4 v = va[j];                                                \
        sst1[(H) * 4 + j] += v.x + v.y + v.z + v.w;                            \
        sst2[(H) * 4 + j] += v.x * v.x + v.y * v.y + v.z * v.z + v.w * v.w;    \
        bf16x4 pk;                                                             \
        pk[0] = (bf16)v.x; pk[1] = (bf16)v.y;                                  \
        pk[2] = (bf16)v.z; pk[3] = (bf16)v.w;                                  \
        *(bf16x4*)&(BUF)[r * 64 + (((c16 >> 1) ^ (r & 7)) * 8) +               \
                         (c16 & 1) * 4] = pk;                                  \
    }

__global__ __launch_bounds__(512, 2) void gemm256f(const float* __restrict__ x,
                                                   const bf16* __restrict__ Gt,
                                                   const float* __restrict__ gw,
                                                   const float* __restrict__ cvec,
                                                   float* __restrict__ out) {
    __shared__ __align__(16) bf16 As[2][256 * 64];   // 32KB per buf
    __shared__ __align__(16) bf16 Bs[2][256 * 64];   // total 128KB
    __shared__ float meanS[256];
    __shared__ float rstdS[256];

    const int tid  = threadIdx.x;
    const int bid  = blockIdx.x;
    // XCD-bijective swizzle (512 % 8 == 0): 64 contiguous wgids per XCD;
    // the 4 dTiles of one mTile land on the same XCD -> x slab L2-resident.
    const int wg   = (bid & 7) * 64 + (bid >> 3);
    const int mT   = wg >> 2;          // 0..127
    const int dT   = wg & 3;
    const int row0 = mT * 256;
    const int col0 = dT * 256;

    const int wave = tid >> 6;
    const int lane = tid & 63;
    const int wm   = wave >> 2;        // 0..1
    const int wn   = wave & 3;         // 0..3
    const int r16  = lane & 15;
    const int g    = lane >> 4;        // k-chunk 0..3 within a K=32 half

    const float* xg = x + (size_t)row0 * KDIM;
    const bf16*  bG = Gt + (size_t)col0 * KDIM;

    f32x4 acc[8][4];
#pragma unroll
    for (int m = 0; m < 8; ++m)
#pragma unroll
        for (int n = 0; n < 4; ++n) acc[m][n] = (f32x4)0.0f;

    float4 va[4];
    float sst1[8] = {0.f, 0.f, 0.f, 0.f, 0.f, 0.f, 0.f, 0.f};
    float sst2[8] = {0.f, 0.f, 0.f, 0.f, 0.f, 0.f, 0.f, 0.f};

    // Prologue: tile 0 -> buf 0.
    A_ISSUE(0, 0)
    stage_half(bG, &Bs[0][0],        0, 0,   tid);
    stage_half(bG, &Bs[0][128 * 64], 0, 128, tid);
    A_WRITE(0, &As[0][0])
    A_ISSUE(1, 0)
    A_WRITE(1, &As[0][0])
    __syncthreads();

    bf16x8 af[4][2], bl[2][2], bh[2][2];

#pragma unroll 1
    for (int t = 0; t < 16; ++t) {
        const int c = t & 1;
        const int o = c ^ 1;
        const bool st = (t < 15);
        const bf16* Ac = &As[c][0];
        const bf16* Bc = &Bs[c][0];

        // ---- p0: Q(m0-3, n0-1); issue A-lo(t+1) regs + gload B-lo(t+1)
#pragma unroll
        for (int m = 0; m < 4; ++m) {
            const int r = m * 32 + wm * 16 + r16;
            af[m][0] = ld_frag(Ac, r, g);
            af[m][1] = ld_frag(Ac, r, 4 + g);
        }
#pragma unroll
        for (int n = 0; n < 2; ++n) {
            const int r = n * 64 + wn * 16 + r16;
            bl[n][0] = ld_frag(Bc, r, g);
            bl[n][1] = ld_frag(Bc, r, 4 + g);
        }
        if (st) {
            A_ISSUE(0, t + 1)
            stage_half(bG, &Bs[o][0], t + 1, 0, tid);
        }
        __builtin_amdgcn_s_barrier();
        MFMA_Q(0, 0, af, bl)
        __builtin_amdgcn_s_barrier();

        // ---- p1: Q(m0-3, n2-3); gload B-hi(t+1)
#pragma unroll
        for (int n = 0; n < 2; ++n) {
            const int r = (n + 2) * 64 + wn * 16 + r16;
            bh[n][0] = ld_frag(Bc, r, g);
            bh[n][1] = ld_frag(Bc, r, 4 + g);
        }
        if (st) stage_half(bG, &Bs[o][128 * 64], t + 1, 128, tid);
        __builtin_amdgcn_s_barrier();
        MFMA_Q(0, 2, af, bh)
        __builtin_amdgcn_s_barrier();

        // ---- p2: Q(m4-7, n2-3); write A-lo(t+1), issue A-hi(t+1)
        if (st) {
            A_WRITE(0, &As[o][0])
            A_ISSUE(1, t + 1)
        }
#pragma unroll
        for (int m = 0; m < 4; ++m) {
            const int r = (m + 4) * 32 + wm * 16 + r16;
            af[m][0] = ld_frag(Ac, r, g);
            af[m][1] = ld_frag(Ac, r, 4 + g);
        }
        __builtin_amdgcn_s_barrier();
        MFMA_Q(4, 2, af, bh)
        __builtin_amdgcn_s_barrier();

        // ---- p3: write A-hi(t+1); syncthreads publishes buf o (and drains
        //          all async gloads + ds_writes); Q(m4-7, n0-1) is reg-only.
        if (st) A_WRITE(1, &As[o][0])
        __syncthreads();
        MFMA_Q(4, 0, af, bl)
    }

    // ---- LN stats finalize: reduce over the 16 threads sharing each row.
#pragma unroll
    for (int i = 0; i < 8; ++i) {
        float a  = sst1[i];
        float b2 = sst2[i];
#pragma unroll
        for (int ofs = 1; ofs < 16; ofs <<= 1) {
            a  += __shfl_xor(a,  ofs, 64);
            b2 += __shfl_xor(b2, ofs, 64);
        }
        if ((tid & 15) == 0) {
            const int r = (i >> 2) * 128 + (i & 3) * 32 + (tid >> 4);
            const float mean = a * (1.0f / KDIM);
            const float var  = b2 * (1.0f / KDIM) - mean * mean;
            meanS[r] = mean;
            rstdS[r] = rsqrtf(var + 1e-5f);
        }
    }
    __syncthreads();

    // ---- Epilogue: LN correction + bias.
#pragma unroll
    for (int n = 0; n < 4; ++n) {
        const int colL = n * 64 + wn * 16 + r16;
        const float cv  = cvec[col0 + colL];
        const float gwv = gw[col0 + colL];
#pragma unroll
        for (int m = 0; m < 8; ++m) {
            const int rbase = m * 32 + wm * 16 + g * 4;
#pragma unroll
            for (int rg = 0; rg < 4; ++rg) {
                const int rowL = rbase + rg;
                out[(size_t)(row0 + rowL) * DDIM + col0 + colL] =
                    rstdS[rowL] * (acc[m][n][rg] - meanS[rowL] * gwv) + cv;
            }
        }
    }
}

// ---------------------------------------------------------------------------
extern "C" void kernel_launch(void* const* d_in, const int* in_sizes, int n_in,
                              void* d_out, int out_size, void* d_ws, size_t ws_size,
                              hipStream_t stream) {
    const float* x     = (const float*)d_in[0];
    const float* w     = (const float*)d_in[1];
    const float* b     = (const float*)d_in[2];
    const float* gamma = (const float*)d_in[3];
    const float* beta  = (const float*)d_in[4];
    float* out = (float*)d_out;

    char* ws = (char*)d_ws;
    // Layout: Gt (2MB) | partG (64KB) | partB (64KB) | gw (4KB) | cvec (4KB)
    bf16*  Gt    = (bf16*)ws;
    float* partG = (float*)(ws + (2u << 20));
    float* partB = (float*)(ws + (2u << 20) + (64u << 10));
    float* gw    = (float*)(ws + (2u << 20) + (128u << 10));
    float* cvec  = (float*)(ws + (2u << 20) + (132u << 10));

    prep_gt<<<dim3(16, 16), 256, 0, stream>>>(w, gamma, Gt);
    prep_part<<<dim3(4, 16), 256, 0, stream>>>(w, gamma, beta, partG, partB);
    prep_reduce<<<4, 256, 0, stream>>>(partG, partB, b, gw, cvec);
    gemm256f<<<dim3(512), 512, 0, stream>>>(x, Gt, gw, cvec, out);
}